// Round 1
// 322.961 us; speedup vs baseline: 1.1563x; 1.1563x over previous
//
#include <hip/hip_runtime.h>
#include <stdint.h>

#define M_ROWS 4096   // BATCH*SEQ
#define N_OUT  4096   // OUT_FEATURES
#define K_IN   4096   // IN_FEATURES
#define NNZ_N  1677722

typedef __attribute__((ext_vector_type(8))) short  bf16x8_t;  // 8 bf16 in 4 VGPRs
typedef __attribute__((ext_vector_type(4))) float  f32x4_t;

// ---------- fp32 -> bf16 (RNE) ----------
__device__ __forceinline__ unsigned short f2bf(float f) {
    union { float f; uint32_t u; } v; v.f = f;
    uint32_t u = v.u;
    u += 0x7FFFu + ((u >> 16) & 1u);   // round-to-nearest-even
    return (unsigned short)(u >> 16);
}

// ---------- fused: zero W_bf16 + convert x to bf16 ----------
// grid covers 16.7M ushorts of W (16B/thread) and 16.7M floats of x (8/thread)
__global__ void zero_and_convert_x(uint4* __restrict__ Wz,
                                   const float4* __restrict__ x,
                                   uint4* __restrict__ xo) {
    int i = blockIdx.x * blockDim.x + threadIdx.x;  // exact-size grid
    uint4 z; z.x = z.y = z.z = z.w = 0u;
    Wz[i] = z;
    float4 a = x[2 * i], b = x[2 * i + 1];
    uint4 o;
    o.x = (uint32_t)f2bf(a.x) | ((uint32_t)f2bf(a.y) << 16);
    o.y = (uint32_t)f2bf(a.z) | ((uint32_t)f2bf(a.w) << 16);
    o.z = (uint32_t)f2bf(b.x) | ((uint32_t)f2bf(b.y) << 16);
    o.w = (uint32_t)f2bf(b.z) | ((uint32_t)f2bf(b.w) << 16);
    xo[i] = o;
}

// ---------- COO scatter-add directly into bf16 W via HW packed-bf16 atomic ----------
// global_atomic_pk_add_bf16 adds a v2bf16; the untouched half gets +0.0 (no-op).
__global__ void scatter_coo_bf16(const float* __restrict__ data,
                                 const int* __restrict__ rows,
                                 const int* __restrict__ cols,
                                 unsigned short* __restrict__ W, int nnz) {
    int i = blockIdx.x * blockDim.x + threadIdx.x;
    if (i < nnz) {
        size_t idx = (size_t)rows[i] * K_IN + cols[i];
        uint32_t hv = (uint32_t)f2bf(data[i]);
        uint32_t pk = (idx & 1) ? (hv << 16) : hv;
        uint32_t* addr = (uint32_t*)(W + (idx & ~(size_t)1));
        asm volatile("global_atomic_pk_add_bf16 %0, %1, off"
                     :: "v"(addr), "v"(pk) : "memory");
    }
}

// ---------- async global->LDS helper (width 16B) ----------
__device__ __forceinline__ void async_ld16(const void* g, void* lds_wave_base) {
    __builtin_amdgcn_global_load_lds(
        (const __attribute__((address_space(1))) uint32_t*)g,
        (__attribute__((address_space(3))) uint32_t*)lds_wave_base,
        16, 0, 0);
}

// stage one 256x64 bf16 tile half (A or B) for K-tile kt into LDS slot:
// 4 x global_load_lds_dwordx4 per thread (512 thr x 16B x 4 = 32 KiB).
// LDS dest is linear (wave-uniform base + lane*16B); the XOR chunk swizzle
// (phys_chunk = chunk ^ (row&7)) is applied on the GLOBAL source address.
#define STAGE_M(gbase, lbase, kt, slot) do {                                   \
    const unsigned short* g_ = (gbase) + (kt) * 64;                            \
    unsigned short*       l_ = (lbase) + (slot) * 32768;                       \
    async_ld16(g_,                  l_);                                       \
    async_ld16(g_ + 1 * 64 * K_IN,  l_ + 4096);                                \
    async_ld16(g_ + 2 * 64 * K_IN,  l_ + 8192);                                \
    async_ld16(g_ + 3 * 64 * K_IN,  l_ + 12288);                               \
} while (0)

// ---------- C[M][N] = A[M][K] * B[N][K]^T, bf16 in, fp32 out ----------
// 256x256 block tile, BK=64, 512 threads = 8 waves (2M x 4N), wave tile 128x64.
// 2-slot LDS double buffer (128 KiB), 4-phase K-step:
//   P1: ds_read af(im0-3)+bf0(jn0-1) | bar | lgkm0 | prio1 16xMFMA prio0 | bar
//   P2: ds_read bf1(jn2-3)           | bar | lgkm0 | prio1 16xMFMA prio0 | bar
//   P3: stage B(kt+2)->slot ; ds_read af(im4-7) | bar | lgkm0 | 16xMFMA | bar
//   P4: stage A(kt+2)->slot ; 16xMFMA ; s_waitcnt vmcnt(8) ; bar
// Invariants: every ds_read of slot `cur` completes by P3's closing barrier
// (lgkm0 precedes it), so P3/P4 prefetch into `cur` is WAR-safe; the counted
// vmcnt(8) leaves exactly K-tile t+2's 8 loads in flight while guaranteeing
// K-tile t+1 fully landed before the next iteration reads it.
__global__ __launch_bounds__(512, 2) void gemm_bt(const unsigned short* __restrict__ A,
                                                  const unsigned short* __restrict__ B,
                                                  float* __restrict__ C) {
    __shared__ __align__(16) unsigned short lds_[65536];  // 128 KiB: [A0|B0|A1|B1]

    const int t    = threadIdx.x;
    const int wave = t >> 6;
    const int lane = t & 63;
    const int wr   = wave >> 2;        // 0..1
    const int wc   = wave & 3;         // 0..3
    const int m0   = blockIdx.y * 256;
    const int n0   = blockIdx.x * 256;

    // staging source: LDS chunk lin = i*512 + t -> (row = lin>>3, phys = t&7),
    // logical chunk = (t&7) ^ (row&7)
    const int srow = t >> 3;
    const int sch  = ((t & 7) ^ (srow & 7)) * 8;
    const unsigned short* gA = A + (size_t)(m0 + srow) * K_IN + sch;
    const unsigned short* gB = B + (size_t)(n0 + srow) * K_IN + sch;
    unsigned short* lA = lds_ + wave * 512;           // wave-uniform dest bases
    unsigned short* lB = lds_ + 16384 + wave * 512;

    // ds_read fragment addressing: row&7 == lane&7, phys_chunk = c ^ (lane&7)
    const int l15  = lane & 15;
    const int aoff = (wr * 128 + l15) * 64;
    const int boff = (wc * 64  + l15) * 64;
    const int ck0  = (((lane >> 4)    ) ^ (lane & 7)) * 8;   // kk=0 (k 0..31)
    const int ck1  = (((lane >> 4) | 4) ^ (lane & 7)) * 8;   // kk=1 (k 32..63)

    f32x4_t acc[8][4];
#pragma unroll
    for (int i = 0; i < 8; ++i)
#pragma unroll
        for (int j = 0; j < 4; ++j) acc[i][j] = (f32x4_t){0.f, 0.f, 0.f, 0.f};

    bf16x8_t af[4][2], bf0[2][2], bf1[2][2];

    // prologue: K-tile0 -> slot0 (8 oldest loads), K-tile1 -> slot1
    STAGE_M(gA, lA, 0, 0); STAGE_M(gB, lB, 0, 0);
    STAGE_M(gA, lA, 1, 1); STAGE_M(gB, lB, 1, 1);
    asm volatile("s_waitcnt vmcnt(8)" ::: "memory");  // K-tile0 landed
    __builtin_amdgcn_s_barrier();

    for (int kt = 0; kt < 64; ++kt) {
        const unsigned short* pA = lds_ + (kt & 1) * 32768;
        const unsigned short* pB = pA + 16384;

        // ---------------- P1 ----------------
#pragma unroll
        for (int im = 0; im < 4; ++im) {
            af[im][0] = *(const bf16x8_t*)(pA + aoff + im * 1024 + ck0);
            af[im][1] = *(const bf16x8_t*)(pA + aoff + im * 1024 + ck1);
        }
#pragma unroll
        for (int jn = 0; jn < 2; ++jn) {
            bf0[jn][0] = *(const bf16x8_t*)(pB + boff + jn * 1024 + ck0);
            bf0[jn][1] = *(const bf16x8_t*)(pB + boff + jn * 1024 + ck1);
        }
        __builtin_amdgcn_s_barrier();
        asm volatile("s_waitcnt lgkmcnt(0)" ::: "memory");
        __builtin_amdgcn_s_setprio(1);
#pragma unroll
        for (int im = 0; im < 4; ++im)
#pragma unroll
            for (int jn = 0; jn < 2; ++jn)
#pragma unroll
                for (int kk = 0; kk < 2; ++kk)
                    acc[im][jn] = __builtin_amdgcn_mfma_f32_16x16x32_bf16(
                        af[im][kk], bf0[jn][kk], acc[im][jn], 0, 0, 0);
        __builtin_amdgcn_s_setprio(0);
        __builtin_amdgcn_s_barrier();

        // ---------------- P2 ----------------
#pragma unroll
        for (int jn = 0; jn < 2; ++jn) {
            bf1[jn][0] = *(const bf16x8_t*)(pB + boff + (2 + jn) * 1024 + ck0);
            bf1[jn][1] = *(const bf16x8_t*)(pB + boff + (2 + jn) * 1024 + ck1);
        }
        __builtin_amdgcn_s_barrier();
        asm volatile("s_waitcnt lgkmcnt(0)" ::: "memory");
        __builtin_amdgcn_s_setprio(1);
#pragma unroll
        for (int im = 0; im < 4; ++im)
#pragma unroll
            for (int jn = 0; jn < 2; ++jn)
#pragma unroll
                for (int kk = 0; kk < 2; ++kk)
                    acc[im][2 + jn] = __builtin_amdgcn_mfma_f32_16x16x32_bf16(
                        af[im][kk], bf1[jn][kk], acc[im][2 + jn], 0, 0, 0);
        __builtin_amdgcn_s_setprio(0);
        __builtin_amdgcn_s_barrier();

        // ---------------- P3 ----------------
        // slot-cur B fully read (P2 lgkm0 + barrier) -> safe to overwrite
        if (kt < 62) STAGE_M(gB, lB, kt + 2, (kt & 1));
#pragma unroll
        for (int im = 0; im < 4; ++im) {
            af[im][0] = *(const bf16x8_t*)(pA + aoff + (4 + im) * 1024 + ck0);
            af[im][1] = *(const bf16x8_t*)(pA + aoff + (4 + im) * 1024 + ck1);
        }
        __builtin_amdgcn_s_barrier();
        asm volatile("s_waitcnt lgkmcnt(0)" ::: "memory");
        __builtin_amdgcn_s_setprio(1);
#pragma unroll
        for (int im = 0; im < 4; ++im)
#pragma unroll
            for (int jn = 0; jn < 2; ++jn)
#pragma unroll
                for (int kk = 0; kk < 2; ++kk)
                    acc[4 + im][jn] = __builtin_amdgcn_mfma_f32_16x16x32_bf16(
                        af[im][kk], bf0[jn][kk], acc[4 + im][jn], 0, 0, 0);
        __builtin_amdgcn_s_setprio(0);
        __builtin_amdgcn_s_barrier();

        // ---------------- P4 ----------------
        // slot-cur A fully read (P3 lgkm0 + barrier) -> safe to overwrite
        if (kt < 62) STAGE_M(gA, lA, kt + 2, (kt & 1));
        __builtin_amdgcn_s_setprio(1);
#pragma unroll
        for (int im = 0; im < 4; ++im)
#pragma unroll
            for (int jn = 0; jn < 2; ++jn)
#pragma unroll
                for (int kk = 0; kk < 2; ++kk)
                    acc[4 + im][2 + jn] = __builtin_amdgcn_mfma_f32_16x16x32_bf16(
                        af[im][kk], bf1[jn][kk], acc[4 + im][2 + jn], 0, 0, 0);
        __builtin_amdgcn_s_setprio(0);
        if (kt < 62) {
            asm volatile("s_waitcnt vmcnt(8)" ::: "memory");  // K-tile kt+1 landed
        } else {
            asm volatile("s_waitcnt vmcnt(0)" ::: "memory");  // drain tail
        }
        __builtin_amdgcn_s_barrier();
    }

    // epilogue: C/D layout col = lane&15, row = (lane>>4)*4 + reg
    const int crow = m0 + wr * 128 + ((lane >> 4) << 2);
    const int ccol = n0 + wc * 64 + l15;
#pragma unroll
    for (int im = 0; im < 8; ++im)
#pragma unroll
        for (int jn = 0; jn < 4; ++jn)
#pragma unroll
            for (int r = 0; r < 4; ++r)
                C[(size_t)(crow + im * 16 + r) * N_OUT + ccol + jn * 16] =
                    acc[im][jn][r];
}

extern "C" void kernel_launch(void* const* d_in, const int* in_sizes, int n_in,
                              void* d_out, int out_size, void* d_ws, size_t ws_size,
                              hipStream_t stream) {
    const float* x    = (const float*)d_in[0];   // [2,2048,4096] fp32
    const float* data = (const float*)d_in[1];   // [NNZ]
    const int*   rows = (const int*)d_in[2];
    const int*   cols = (const int*)d_in[3];
    float*       out  = (float*)d_out;           // [2,2048,4096] fp32

    // workspace layout: W_bf16 32 MiB | x_bf16 32 MiB
    unsigned short* W_bf16 = (unsigned short*)d_ws;
    unsigned short* x_bf16 = (unsigned short*)((char*)d_ws + (32u << 20));

    // 1. fused: zero bf16 W + convert x -> bf16 (16.7M elems each, 8/thread)
    zero_and_convert_x<<<(N_OUT * K_IN) / (8 * 256), 256, 0, stream>>>(
        (uint4*)W_bf16, (const float4*)x, (uint4*)x_bf16);

    // 2. scatter COO -> bf16 W via packed-bf16 HW atomic
    scatter_coo_bf16<<<(NNZ_N + 255) / 256, 256, 0, stream>>>(
        data, rows, cols, W_bf16, NNZ_N);

    // 3. y = x * W^T via bf16 MFMA GEMM (256x256 tile, 8-wave phase-split)
    dim3 grid(N_OUT / 256, M_ROWS / 256);  // 16 x 16 = 256 blocks = 1/CU
    gemm_bt<<<grid, 512, 0, stream>>>(x_bf16, W_bf16, out);
}